// Round 11
// baseline (264.204 us; speedup 1.0000x reference)
//
#include <hip/hip_runtime.h>
#include <hip/hip_fp16.h>

#define NB 64
#define NS 512
#define NH 1024
#define NITERS 10

// -log(512)
#define LOG_INV_NS (-6.238324625039508f)

using half8 = _Float16 __attribute__((ext_vector_type(8)));
using f32x4 = float __attribute__((ext_vector_type(4)));

// ---------------------------------------------------------------------------
// Fused kernel: batched cosine-score GEMM straight from fp32 inputs.
//   S[b][m][n] = (x[b][m].y[b][n]) / (||x[b][m]|| ||y[b][n]||), f16 out.
// 256x128 tile, 8 tiles/batch -> 512 blocks = 2 blocks/CU so one block's
// compute overlaps the other's barrier/memory stalls (the round-10 1-block/CU
// lockstep was ~85% stalled). 256 threads / 4 waves (2Mx2N, wave = 128x64).
// BK=32, LDS double-buffer (1 barrier/step), register prefetch, in-kernel
// row norms, epilogue normalization, XCD-pinned block decode (blk%8 = b%8).
__global__ __launch_bounds__(256) void gemm_fused(
    const float* __restrict__ x, const float* __restrict__ y,
    _Float16* __restrict__ Sh) {
  __shared__ _Float16 As[2][256][40];   // 40960 B
  __shared__ _Float16 Bs[2][128][40];   // 20480 B
  __shared__ float invA[256], invB[128];

  int blk = blockIdx.x;
  int b = blk & 63;                  // batch; blk%8 = b%8 -> XCD pinned
  int tile = blk >> 6;               // 0..7 = 2M x 4N
  int tm = (tile >> 2) * 256, tn = (tile & 3) * 128;
  int tid = threadIdx.x;
  int wid = tid >> 6, lane = tid & 63;
  int wr = (wid >> 1) * 128;         // {0,128}
  int wc = (wid & 1) * 64;           // {0,64}
  int fr = lane & 15, fq = lane >> 4;

  // staging: A rows srow and srow+128, B row srow; k-half skh in {0,16}.
  int srow = tid >> 1;               // 0..127
  int skh = (tid & 1) * 16;
  const float* xb0 = x + ((size_t)b * NS + tm + srow) * NH + skh;
  const float* xb1 = xb0 + (size_t)128 * NH;
  const float* yb = y + ((size_t)b * NS + tn + srow) * NH + skh;

  f32x4 acc[8][4] = {};
  float4 rx0[4], rx1[4], ry[4];
  float sq0 = 0.f, sq1 = 0.f, sqy = 0.f;

#define GLOAD(K0)                                                     \
  do {                                                                \
    const float4* p0 = (const float4*)(xb0 + (K0));                   \
    const float4* p1 = (const float4*)(xb1 + (K0));                   \
    const float4* py = (const float4*)(yb + (K0));                    \
    rx0[0] = p0[0]; rx0[1] = p0[1]; rx0[2] = p0[2]; rx0[3] = p0[3];   \
    rx1[0] = p1[0]; rx1[1] = p1[1]; rx1[2] = p1[2]; rx1[3] = p1[3];   \
    ry[0] = py[0]; ry[1] = py[1]; ry[2] = py[2]; ry[3] = py[3];       \
  } while (0)

#define CAST_WRITE(BUF)                                               \
  do {                                                                \
    alignas(16) _Float16 t0[16];                                      \
    alignas(16) _Float16 t1[16];                                      \
    alignas(16) _Float16 tb[16];                                      \
    _Pragma("unroll") for (int j = 0; j < 4; ++j) {                   \
      float4 v = rx0[j];                                              \
      t0[4 * j + 0] = (_Float16)v.x; t0[4 * j + 1] = (_Float16)v.y;   \
      t0[4 * j + 2] = (_Float16)v.z; t0[4 * j + 3] = (_Float16)v.w;   \
      sq0 += v.x * v.x + v.y * v.y + v.z * v.z + v.w * v.w;           \
    }                                                                 \
    _Pragma("unroll") for (int j = 0; j < 4; ++j) {                   \
      float4 v = rx1[j];                                              \
      t1[4 * j + 0] = (_Float16)v.x; t1[4 * j + 1] = (_Float16)v.y;   \
      t1[4 * j + 2] = (_Float16)v.z; t1[4 * j + 3] = (_Float16)v.w;   \
      sq1 += v.x * v.x + v.y * v.y + v.z * v.z + v.w * v.w;           \
    }                                                                 \
    _Pragma("unroll") for (int j = 0; j < 4; ++j) {                   \
      float4 v = ry[j];                                               \
      tb[4 * j + 0] = (_Float16)v.x; tb[4 * j + 1] = (_Float16)v.y;   \
      tb[4 * j + 2] = (_Float16)v.z; tb[4 * j + 3] = (_Float16)v.w;   \
      sqy += v.x * v.x + v.y * v.y + v.z * v.z + v.w * v.w;           \
    }                                                                 \
    *(half8*)&As[BUF][srow][skh + 0] = *(half8*)&t0[0];               \
    *(half8*)&As[BUF][srow][skh + 8] = *(half8*)&t0[8];               \
    *(half8*)&As[BUF][128 + srow][skh + 0] = *(half8*)&t1[0];         \
    *(half8*)&As[BUF][128 + srow][skh + 8] = *(half8*)&t1[8];         \
    *(half8*)&Bs[BUF][srow][skh + 0] = *(half8*)&tb[0];               \
    *(half8*)&Bs[BUF][srow][skh + 8] = *(half8*)&tb[8];               \
  } while (0)

  // prologue: stage chunk 0 into buf 0, prefetch chunk 1 into regs
  GLOAD(0);
  CAST_WRITE(0);
  GLOAD(32);

  for (int s = 0; s < 32; ++s) {
    __syncthreads();                 // buf[s&1] staged; buf[s&1^1] drained
    int cur = s & 1;
    if (s < 31) {
      CAST_WRITE(cur ^ 1);           // stage chunk s+1 (overlaps MFMA below)
      if (s < 30) GLOAD((s + 2) * 32);  // prefetch chunk s+2
    }
    half8 bf[4];
#pragma unroll
    for (int j = 0; j < 4; ++j)
      bf[j] = *(const half8*)&Bs[cur][wc + 16 * j + fr][8 * fq];
#pragma unroll
    for (int i = 0; i < 8; ++i) {
      half8 af = *(const half8*)&As[cur][wr + 16 * i + fr][8 * fq];
#pragma unroll
      for (int j = 0; j < 4; ++j)
        acc[i][j] = __builtin_amdgcn_mfma_f32_16x16x32_f16(af, bf[j], acc[i][j], 0, 0, 0);
    }
  }
#undef GLOAD
#undef CAST_WRITE

  // finalize row norms: two partials per row in adjacent lanes (tid, tid^1)
  sq0 += __shfl_xor(sq0, 1, 64);
  sq1 += __shfl_xor(sq1, 1, 64);
  sqy += __shfl_xor(sqy, 1, 64);
  if ((tid & 1) == 0) {
    invA[srow] = 1.0f / fmaxf(sqrtf(sq0), 1e-12f);
    invA[128 + srow] = 1.0f / fmaxf(sqrtf(sq1), 1e-12f);
    invB[srow] = 1.0f / fmaxf(sqrtf(sqy), 1e-12f);
  }
  __syncthreads();  // invA/invB visible to all waves

  // Epilogue: S = acc * invA[m] * invB[n], direct f16 stores.
  // C/D layout: col = lane&15 (n), row = (lane>>4)*4 + reg (m).
  _Float16* Sb = Sh + (size_t)b * NS * NS;
#pragma unroll
  for (int i = 0; i < 8; ++i)
#pragma unroll
    for (int j = 0; j < 4; ++j) {
      int rr = wr + 16 * i + 4 * fq;
      int cc = wc + 16 * j + fr;
      float ib = invB[cc];
#pragma unroll
      for (int p = 0; p < 4; ++p)
        Sb[(size_t)(tm + rr + p) * NS + tn + cc] =
            (_Float16)(acc[i][j][p] * invA[rr + p] * ib);
    }
}

// ---------------------------------------------------------------------------
// Kernel 3: init V=0, W=log_nu
__global__ __launch_bounds__(256) void init_kernel(float* __restrict__ V, float* __restrict__ W) {
  int i = blockIdx.x * 256 + threadIdx.x;  // 32768
  V[i] = 0.f;
  W[i] = LOG_INV_NS;
}

// ---------------------------------------------------------------------------
// Kernel 4 (u/row step): U[b][m] = log_mu - log( sum_n exp(f*S[b][m][n] + W[b][n]) )
__global__ __launch_bounds__(256) void u_kernel(
    const _Float16* __restrict__ Sh, const float* __restrict__ W,
    float* __restrict__ U, float f) {
  __shared__ float Wt[8][65];
  int blk = blockIdx.x;
  int bs = blk & 7, rest = blk >> 3;
  int rowgrp = rest & 31, bq = rest >> 5;
  int b = bq * 8 + bs;
  int t = threadIdx.x;
#pragma unroll
  for (int i = 0; i < 2; ++i) {
    int idx = t + 256 * i;
    Wt[idx & 7][idx >> 3] = W[b * NS + idx];
  }
  __syncthreads();
  int w = t >> 6, l = t & 63;
  float wn[8];
#pragma unroll
  for (int e = 0; e < 8; ++e) wn[e] = Wt[e][l];
  int m0 = rowgrp * 16 + w * 4;
  const _Float16* Sb = Sh + ((size_t)b * NS + m0) * NS + 8 * l;
  float sum[4] = {0.f, 0.f, 0.f, 0.f};
#pragma unroll
  for (int k = 0; k < 4; ++k) {
    half8 hv = *(const half8*)(Sb + (size_t)k * NS);
#pragma unroll
    for (int e = 0; e < 8; ++e) sum[k] += __expf(fmaf(f, (float)hv[e], wn[e]));
  }
#pragma unroll
  for (int o = 32; o; o >>= 1) {
#pragma unroll
    for (int k = 0; k < 4; ++k) sum[k] += __shfl_xor(sum[k], o, 64);
  }
  if (l == 0) {
#pragma unroll
    for (int k = 0; k < 4; ++k)
      U[b * NS + m0 + k] = LOG_INV_NS - __logf(sum[k]);
  }
}

// ---------------------------------------------------------------------------
// Kernel 5 (v/col step)
__global__ __launch_bounds__(256) void v_kernel(
    const _Float16* __restrict__ Sh, const float* __restrict__ U,
    float* __restrict__ V, float* __restrict__ W,
    float f, int last, float* __restrict__ outPart) {
  __shared__ float Ul[NS];
  __shared__ float partC[16][128];
  __shared__ float partD[16][128];
  __shared__ float red[128];
  int blk = blockIdx.x;
  int bs = blk & 7, rest = blk >> 3;
  int q = rest & 3, bq = rest >> 2;
  int b = bq * 8 + bs;
  int t = threadIdx.x;
  Ul[t] = U[b * NS + t];
  Ul[t + 256] = U[b * NS + t + 256];
  __syncthreads();

  int r = t >> 4, cg = t & 15;
  const _Float16* Sb = Sh + (size_t)b * NS * NS + q * 128 + cg * 8;
  float c[8] = {}, d[8] = {};
  if (!last) {
#pragma unroll 4
    for (int s = 0; s < 32; ++s) {
      int m = s * 16 + r;
      half8 hv = *(const half8*)(Sb + (size_t)m * NS);
      float um = Ul[m];
#pragma unroll
      for (int e = 0; e < 8; ++e) c[e] += __expf(fmaf(f, (float)hv[e], um));
    }
  } else {
#pragma unroll 2
    for (int s = 0; s < 32; ++s) {
      int m = s * 16 + r;
      half8 hv = *(const half8*)(Sb + (size_t)m * NS);
      float um = Ul[m];
#pragma unroll
      for (int e = 0; e < 8; ++e) {
        float sv = (float)hv[e];
        float ev = __expf(fmaf(f, sv, um));
        c[e] += ev;
        d[e] = fmaf(sv, ev, d[e]);
      }
    }
  }
  *(f32x4*)&partC[r][cg * 8 + 0] = f32x4{c[0], c[1], c[2], c[3]};
  *(f32x4*)&partC[r][cg * 8 + 4] = f32x4{c[4], c[5], c[6], c[7]};
  if (last) {
    *(f32x4*)&partD[r][cg * 8 + 0] = f32x4{d[0], d[1], d[2], d[3]};
    *(f32x4*)&partD[r][cg * 8 + 4] = f32x4{d[4], d[5], d[6], d[7]};
  }
  __syncthreads();
  if (t < 128) {
    float ct = 0.f;
#pragma unroll
    for (int r2 = 0; r2 < 16; ++r2) ct += partC[r2][t];
    float vnew = LOG_INV_NS - __logf(ct);
    int n = b * NS + q * 128 + t;
    float vold = V[n];
    V[n] = vnew;
    W[n] = 2.f * vnew - vold;
    if (last) {
      float dt = 0.f;
#pragma unroll
      for (int r2 = 0; r2 < 16; ++r2) dt += partD[r2][t];
      red[t] = dt / ct;
    }
  }
  if (last) {
    __syncthreads();
    for (int s2 = 64; s2 > 0; s2 >>= 1) {
      if (t < s2) red[t] += red[t + s2];
      __syncthreads();
    }
    if (t == 0) outPart[b * 4 + q] = red[0] * (1.0f / (float)NS);
  }
}

// ---------------------------------------------------------------------------
// Kernel 6: combine 4 partials per batch (deterministic)
__global__ void combine_kernel(const float* __restrict__ outPart, float* __restrict__ out) {
  int b = threadIdx.x;  // 64 threads
  out[b] = outPart[4 * b] + outPart[4 * b + 1] + outPart[4 * b + 2] + outPart[4 * b + 3];
}

// ---------------------------------------------------------------------------
extern "C" void kernel_launch(void* const* d_in, const int* in_sizes, int n_in,
                              void* d_out, int out_size, void* d_ws, size_t ws_size,
                              hipStream_t stream) {
  (void)in_sizes; (void)n_in; (void)out_size; (void)ws_size;
  const float* x = (const float*)d_in[0];
  const float* y = (const float*)d_in[1];
  float* out = (float*)d_out;

  char* ws = (char*)d_ws;
  _Float16* Sh = (_Float16*)ws;                                // 32 MiB
  float* fregion = (float*)(ws + (size_t)NB * NS * NS * 2);
  float* U = fregion;                                          // 32768
  float* V = U + NB * NS;
  float* W = V + NB * NS;
  float* outPart = W + NB * NS;                                // 256

  gemm_fused<<<512, 256, 0, stream>>>(x, y, Sh);
  init_kernel<<<(NB * NS) / 256, 256, 0, stream>>>(V, W);

  for (int t = 1; t <= NITERS; ++t) {
    float f = 10.0f * (float)t;
    u_kernel<<<2048, 256, 0, stream>>>(Sh, W, U, f);
    v_kernel<<<256, 256, 0, stream>>>(Sh, U, V, W, f, t == NITERS ? 1 : 0, outPart);
  }
  combine_kernel<<<1, 64, 0, stream>>>(outPart, out);
}

// Round 12
// 213.999 us; speedup vs baseline: 1.2346x; 1.2346x over previous
//
#include <hip/hip_runtime.h>
#include <hip/hip_fp16.h>

#define NB 64
#define NS 512
#define NH 1024
#define NITERS 10

// -log(512)
#define LOG_INV_NS (-6.238324625039508f)

using half8 = _Float16 __attribute__((ext_vector_type(8)));
using f32x4 = float __attribute__((ext_vector_type(4)));

// ---------------------------------------------------------------------------
// Fused GEMM (R10 verbatim, 112us proven): batched cosine scores, f16 out.
// 256x256 tile, 512 thr / 8 waves, BK=32, LDS double-buffer, reg prefetch,
// in-kernel row norms, epilogue normalization, XCD-pinned decode.
__global__ __launch_bounds__(512) void gemm_fused(
    const float* __restrict__ x, const float* __restrict__ y,
    _Float16* __restrict__ Sh) {
  __shared__ _Float16 As[2][256][40];
  __shared__ _Float16 Bs[2][256][40];
  __shared__ float invA[256], invB[256];

  int blk = blockIdx.x;
  int b = blk & 63;                  // batch; blk%8 = b%8 -> XCD pinned
  int tile = blk >> 6;               // 0..3
  int tm = (tile >> 1) * 256, tn = (tile & 1) * 256;
  int tid = threadIdx.x;
  int wid = tid >> 6, lane = tid & 63;
  int wr = (wid >> 2) * 128;         // {0,128}
  int wc = (wid & 3) * 64;           // {0,64,128,192}
  int fr = lane & 15, fq = lane >> 4;

  int srow = tid >> 1;
  int skh = (tid & 1) * 16;
  const float* xb = x + ((size_t)b * NS + tm + srow) * NH + skh;
  const float* yb = y + ((size_t)b * NS + tn + srow) * NH + skh;

  f32x4 acc[8][4] = {};
  float4 rx[4], ry[4];
  float sqx = 0.f, sqy = 0.f;

#define GLOAD(K0)                                                     \
  do {                                                                \
    const float4* px = (const float4*)(xb + (K0));                    \
    const float4* py = (const float4*)(yb + (K0));                    \
    rx[0] = px[0]; rx[1] = px[1]; rx[2] = px[2]; rx[3] = px[3];       \
    ry[0] = py[0]; ry[1] = py[1]; ry[2] = py[2]; ry[3] = py[3];       \
  } while (0)

#define CAST_WRITE(BUF)                                               \
  do {                                                                \
    alignas(16) _Float16 ta[16];                                      \
    alignas(16) _Float16 tb[16];                                      \
    _Pragma("unroll") for (int j = 0; j < 4; ++j) {                   \
      float4 v = rx[j];                                               \
      ta[4 * j + 0] = (_Float16)v.x; ta[4 * j + 1] = (_Float16)v.y;   \
      ta[4 * j + 2] = (_Float16)v.z; ta[4 * j + 3] = (_Float16)v.w;   \
      sqx += v.x * v.x + v.y * v.y + v.z * v.z + v.w * v.w;           \
    }                                                                 \
    _Pragma("unroll") for (int j = 0; j < 4; ++j) {                   \
      float4 v = ry[j];                                               \
      tb[4 * j + 0] = (_Float16)v.x; tb[4 * j + 1] = (_Float16)v.y;   \
      tb[4 * j + 2] = (_Float16)v.z; tb[4 * j + 3] = (_Float16)v.w;   \
      sqy += v.x * v.x + v.y * v.y + v.z * v.z + v.w * v.w;           \
    }                                                                 \
    *(half8*)&As[BUF][srow][skh + 0] = *(half8*)&ta[0];               \
    *(half8*)&As[BUF][srow][skh + 8] = *(half8*)&ta[8];               \
    *(half8*)&Bs[BUF][srow][skh + 0] = *(half8*)&tb[0];               \
    *(half8*)&Bs[BUF][srow][skh + 8] = *(half8*)&tb[8];               \
  } while (0)

  GLOAD(0);
  CAST_WRITE(0);
  GLOAD(32);

  for (int s = 0; s < 32; ++s) {
    __syncthreads();
    int cur = s & 1;
    if (s < 31) {
      CAST_WRITE(cur ^ 1);
      if (s < 30) GLOAD((s + 2) * 32);
    }
    half8 bf[4];
#pragma unroll
    for (int j = 0; j < 4; ++j)
      bf[j] = *(const half8*)&Bs[cur][wc + 16 * j + fr][8 * fq];
#pragma unroll
    for (int i = 0; i < 8; ++i) {
      half8 af = *(const half8*)&As[cur][wr + 16 * i + fr][8 * fq];
#pragma unroll
      for (int j = 0; j < 4; ++j)
        acc[i][j] = __builtin_amdgcn_mfma_f32_16x16x32_f16(af, bf[j], acc[i][j], 0, 0, 0);
    }
  }
#undef GLOAD
#undef CAST_WRITE

  sqx += __shfl_xor(sqx, 1, 64);
  sqy += __shfl_xor(sqy, 1, 64);
  if ((tid & 1) == 0) {
    invA[srow] = 1.0f / fmaxf(sqrtf(sqx), 1e-12f);
    invB[srow] = 1.0f / fmaxf(sqrtf(sqy), 1e-12f);
  }
  __syncthreads();

  _Float16* Sb = Sh + (size_t)b * NS * NS;
#pragma unroll
  for (int i = 0; i < 8; ++i)
#pragma unroll
    for (int j = 0; j < 4; ++j) {
      int rr = wr + 16 * i + 4 * fq;
      int cc = wc + 16 * j + fr;
      float ib = invB[cc];
#pragma unroll
      for (int p = 0; p < 4; ++p)
        Sb[(size_t)(tm + rr + p) * NS + tn + cc] =
            (_Float16)(acc[i][j][p] * invA[rr + p] * ib);
    }
}

// ---------------------------------------------------------------------------
// Kernel 3: init V=0, W=log_nu
__global__ __launch_bounds__(256) void init_kernel(float* __restrict__ V, float* __restrict__ W) {
  int i = blockIdx.x * 256 + threadIdx.x;  // 32768
  V[i] = 0.f;
  W[i] = LOG_INV_NS;
}

// ---------------------------------------------------------------------------
// Kernel 4 (u/row step): unchanged (2048 blocks, 8 blocks/CU, coalesced).
__global__ __launch_bounds__(256) void u_kernel(
    const _Float16* __restrict__ Sh, const float* __restrict__ W,
    float* __restrict__ U, float f) {
  __shared__ float Wt[8][65];
  int blk = blockIdx.x;
  int bs = blk & 7, rest = blk >> 3;
  int rowgrp = rest & 31, bq = rest >> 5;
  int b = bq * 8 + bs;
  int t = threadIdx.x;
#pragma unroll
  for (int i = 0; i < 2; ++i) {
    int idx = t + 256 * i;
    Wt[idx & 7][idx >> 3] = W[b * NS + idx];
  }
  __syncthreads();
  int w = t >> 6, l = t & 63;
  float wn[8];
#pragma unroll
  for (int e = 0; e < 8; ++e) wn[e] = Wt[e][l];
  int m0 = rowgrp * 16 + w * 4;
  const _Float16* Sb = Sh + ((size_t)b * NS + m0) * NS + 8 * l;
  float sum[4] = {0.f, 0.f, 0.f, 0.f};
#pragma unroll
  for (int k = 0; k < 4; ++k) {
    half8 hv = *(const half8*)(Sb + (size_t)k * NS);
#pragma unroll
    for (int e = 0; e < 8; ++e) sum[k] += __expf(fmaf(f, (float)hv[e], wn[e]));
  }
#pragma unroll
  for (int o = 32; o; o >>= 1) {
#pragma unroll
    for (int k = 0; k < 4; ++k) sum[k] += __shfl_xor(sum[k], o, 64);
  }
  if (l == 0) {
#pragma unroll
    for (int k = 0; k < 4; ++k)
      U[b * NS + m0 + k] = LOG_INV_NS - __logf(sum[k]);
  }
}

// ---------------------------------------------------------------------------
// Kernel 5 (v/col step) REWRITTEN for occupancy: 1024 blocks (64 b x 16
// col-groups of 32), 256 threads; thread reads 8 rows x half8 (full 64B line
// per 4-lane group); partial col-sums -> LDS matrix -> shfl(32) -> 4-wave
// combine. 4 blocks/CU vs old 1 block/CU.
__global__ __launch_bounds__(256) void v_kernel(
    const _Float16* __restrict__ Sh, const float* __restrict__ U,
    float* __restrict__ V, float* __restrict__ W,
    float f, int last, float* __restrict__ outPart) {
  __shared__ float Ul[NS];
  __shared__ float partC[64][33];
  __shared__ float partD[64][33];
  __shared__ float redC[4][33];
  __shared__ float redD[4][33];
  int blk = blockIdx.x;
  int b = blk & 63;                 // blk%8 = b%8 -> XCD-consistent with gemm
  int ng = blk >> 6;                // 0..15, 32 cols each
  int t = threadIdx.x;
  Ul[t] = U[b * NS + t];
  Ul[t + 256] = U[b * NS + t + 256];
  __syncthreads();

  int oct = t & 3;                  // half8 within the 32-col group
  int mc = t >> 2;                  // m-chunk (8 rows each), 0..63
  const _Float16* Sb = Sh + (size_t)b * NS * NS + (size_t)(mc * 8) * NS + ng * 32 + oct * 8;
  float c[8] = {}, d[8] = {};
#pragma unroll
  for (int i = 0; i < 8; ++i) {
    half8 hv = *(const half8*)(Sb + (size_t)i * NS);
    float um = Ul[mc * 8 + i];
#pragma unroll
    for (int e = 0; e < 8; ++e) {
      float sv = (float)hv[e];
      float ev = __expf(fmaf(f, sv, um));
      c[e] += ev;
      d[e] = fmaf(sv, ev, d[e]);
    }
  }
#pragma unroll
  for (int e = 0; e < 8; ++e) {
    partC[mc][oct * 8 + e] = c[e];
    partD[mc][oct * 8 + e] = d[e];
  }
  __syncthreads();
  {
    int ci = t & 31, seg = t >> 5;  // 8 segs x 8 chunks
    float cc = 0.f, dd = 0.f;
#pragma unroll
    for (int k = 0; k < 8; ++k) {
      cc += partC[seg * 8 + k][ci];
      dd += partD[seg * 8 + k][ci];
    }
    cc += __shfl_xor(cc, 32, 64);   // combine seg pairs within wave
    dd += __shfl_xor(dd, 32, 64);
    int w = t >> 6, l = t & 63;
    if (l < 32) { redC[w][l] = cc; redD[w][l] = dd; }
  }
  __syncthreads();
  if (t < 32) {
    float cc = redC[0][t] + redC[1][t] + redC[2][t] + redC[3][t];
    float vnew = LOG_INV_NS - __logf(cc);
    int n = b * NS + ng * 32 + t;
    float vold = V[n];
    V[n] = vnew;
    W[n] = 2.f * vnew - vold;
    if (last) {
      float dd = redD[0][t] + redD[1][t] + redD[2][t] + redD[3][t];
      float r = dd / cc;
      // reduce 32 values within wave 0 (masks stay inside active lanes 0-31)
      r += __shfl_xor(r, 16, 64);
      r += __shfl_xor(r, 8, 64);
      r += __shfl_xor(r, 4, 64);
      r += __shfl_xor(r, 2, 64);
      r += __shfl_xor(r, 1, 64);
      if (t == 0) outPart[b * 16 + ng] = r * (1.0f / (float)NS);
    }
  }
}

// ---------------------------------------------------------------------------
// Kernel 6: combine 16 partials per batch (deterministic)
__global__ void combine_kernel(const float* __restrict__ outPart, float* __restrict__ out) {
  int b = threadIdx.x;  // 64 threads
  float s = 0.f;
#pragma unroll
  for (int k = 0; k < 16; ++k) s += outPart[b * 16 + k];
  out[b] = s;
}

// ---------------------------------------------------------------------------
extern "C" void kernel_launch(void* const* d_in, const int* in_sizes, int n_in,
                              void* d_out, int out_size, void* d_ws, size_t ws_size,
                              hipStream_t stream) {
  (void)in_sizes; (void)n_in; (void)out_size; (void)ws_size;
  const float* x = (const float*)d_in[0];
  const float* y = (const float*)d_in[1];
  float* out = (float*)d_out;

  char* ws = (char*)d_ws;
  _Float16* Sh = (_Float16*)ws;                                // 32 MiB
  float* fregion = (float*)(ws + (size_t)NB * NS * NS * 2);
  float* U = fregion;                                          // 32768
  float* V = U + NB * NS;
  float* W = V + NB * NS;
  float* outPart = W + NB * NS;                                // 1024

  gemm_fused<<<256, 512, 0, stream>>>(x, y, Sh);
  init_kernel<<<(NB * NS) / 256, 256, 0, stream>>>(V, W);

  for (int t = 1; t <= NITERS; ++t) {
    float f = 10.0f * (float)t;
    u_kernel<<<2048, 256, 0, stream>>>(Sh, W, U, f);
    v_kernel<<<1024, 256, 0, stream>>>(Sh, U, V, W, f, t == NITERS ? 1 : 0, outPart);
  }
  combine_kernel<<<1, 64, 0, stream>>>(outPart, out);
}

// Round 13
// 193.176 us; speedup vs baseline: 1.3677x; 1.1078x over previous
//
#include <hip/hip_runtime.h>
#include <hip/hip_fp16.h>

#define NB 64
#define NS 512
#define NH 1024
#define NITERS 10

// -log(512)
#define LOG_INV_NS (-6.238324625039508f)

using half8 = _Float16 __attribute__((ext_vector_type(8)));
using f32x4 = float __attribute__((ext_vector_type(4)));

// ---------------------------------------------------------------------------
// Fused GEMM: batched cosine scores, f16 out. 256x256 tile, 512 thr / 8 waves,
// BK=32, LDS double-buffer. R13 change: per-step order is
//   MFMA(buf cur) -> CAST_WRITE(buf nxt) -> GLOAD(chunk+2) -> lgkmcnt(0) -> raw s_barrier
// so the compiler's vmcnt drain (at the rx/ry use in CAST_WRITE) lands AFTER
// the MFMA phase, and the barrier itself (raw s_barrier, not __syncthreads)
// no longer drains vmcnt -> prefetched loads stay in flight across the MFMA.
__global__ __launch_bounds__(512) void gemm_fused(
    const float* __restrict__ x, const float* __restrict__ y,
    _Float16* __restrict__ Sh) {
  __shared__ _Float16 As[2][256][40];
  __shared__ _Float16 Bs[2][256][40];
  __shared__ float invA[256], invB[256];

  int blk = blockIdx.x;
  int b = blk & 63;                  // batch; blk%8 = b%8 -> XCD pinned
  int tile = blk >> 6;               // 0..3
  int tm = (tile >> 1) * 256, tn = (tile & 1) * 256;
  int tid = threadIdx.x;
  int wid = tid >> 6, lane = tid & 63;
  int wr = (wid >> 2) * 128;         // {0,128}
  int wc = (wid & 3) * 64;           // {0,64,128,192}
  int fr = lane & 15, fq = lane >> 4;

  int srow = tid >> 1;
  int skh = (tid & 1) * 16;
  const float* xb = x + ((size_t)b * NS + tm + srow) * NH + skh;
  const float* yb = y + ((size_t)b * NS + tn + srow) * NH + skh;

  f32x4 acc[8][4] = {};
  float4 rx[4], ry[4];
  float sqx = 0.f, sqy = 0.f;

#define GLOAD(K0)                                                     \
  do {                                                                \
    const float4* px = (const float4*)(xb + (K0));                    \
    const float4* py = (const float4*)(yb + (K0));                    \
    rx[0] = px[0]; rx[1] = px[1]; rx[2] = px[2]; rx[3] = px[3];       \
    ry[0] = py[0]; ry[1] = py[1]; ry[2] = py[2]; ry[3] = py[3];       \
  } while (0)

#define CAST_WRITE(BUF)                                               \
  do {                                                                \
    alignas(16) _Float16 ta[16];                                      \
    alignas(16) _Float16 tb[16];                                      \
    _Pragma("unroll") for (int j = 0; j < 4; ++j) {                   \
      float4 v = rx[j];                                               \
      ta[4 * j + 0] = (_Float16)v.x; ta[4 * j + 1] = (_Float16)v.y;   \
      ta[4 * j + 2] = (_Float16)v.z; ta[4 * j + 3] = (_Float16)v.w;   \
      sqx += v.x * v.x + v.y * v.y + v.z * v.z + v.w * v.w;           \
    }                                                                 \
    _Pragma("unroll") for (int j = 0; j < 4; ++j) {                   \
      float4 v = ry[j];                                               \
      tb[4 * j + 0] = (_Float16)v.x; tb[4 * j + 1] = (_Float16)v.y;   \
      tb[4 * j + 2] = (_Float16)v.z; tb[4 * j + 3] = (_Float16)v.w;   \
      sqy += v.x * v.x + v.y * v.y + v.z * v.z + v.w * v.w;           \
    }                                                                 \
    *(half8*)&As[BUF][srow][skh + 0] = *(half8*)&ta[0];               \
    *(half8*)&As[BUF][srow][skh + 8] = *(half8*)&ta[8];               \
    *(half8*)&Bs[BUF][srow][skh + 0] = *(half8*)&tb[0];               \
    *(half8*)&Bs[BUF][srow][skh + 8] = *(half8*)&tb[8];               \
  } while (0)

  // prologue: stage chunk 0 into buf 0, issue chunk 1 loads
  GLOAD(0);
  CAST_WRITE(0);
  GLOAD(32);
  asm volatile("s_waitcnt lgkmcnt(0)" ::: "memory");
  __builtin_amdgcn_sched_barrier(0);
  __builtin_amdgcn_s_barrier();
  __builtin_amdgcn_sched_barrier(0);

  for (int s = 0; s < 32; ++s) {
    int cur = s & 1;
    // ---- MFMA phase on buf[cur] (loads for chunk s+1 still in flight) ----
    half8 bf[4];
#pragma unroll
    for (int j = 0; j < 4; ++j)
      bf[j] = *(const half8*)&Bs[cur][wc + 16 * j + fr][8 * fq];
#pragma unroll
    for (int i = 0; i < 8; ++i) {
      half8 af = *(const half8*)&As[cur][wr + 16 * i + fr][8 * fq];
#pragma unroll
      for (int j = 0; j < 4; ++j)
        acc[i][j] = __builtin_amdgcn_mfma_f32_16x16x32_f16(af, bf[j], acc[i][j], 0, 0, 0);
    }
    // ---- stage chunk s+1 into buf[cur^1]; issue loads for chunk s+2 ----
    if (s < 31) {
      CAST_WRITE(cur ^ 1);             // compiler waits vmcnt here (after MFMA)
      if (s < 30) GLOAD((s + 2) * 32);
    }
    asm volatile("s_waitcnt lgkmcnt(0)" ::: "memory");
    __builtin_amdgcn_sched_barrier(0);
    __builtin_amdgcn_s_barrier();
    __builtin_amdgcn_sched_barrier(0);
  }
#undef GLOAD
#undef CAST_WRITE

  // finalize row norms: two partials per row in adjacent lanes (tid, tid^1)
  sqx += __shfl_xor(sqx, 1, 64);
  sqy += __shfl_xor(sqy, 1, 64);
  if ((tid & 1) == 0) {
    invA[srow] = 1.0f / fmaxf(sqrtf(sqx), 1e-12f);
    invB[srow] = 1.0f / fmaxf(sqrtf(sqy), 1e-12f);
  }
  __syncthreads();

  // Epilogue: S = acc * invA[m] * invB[n], direct f16 stores.
  // C/D layout: col = lane&15 (n), row = (lane>>4)*4 + reg (m).
  _Float16* Sb = Sh + (size_t)b * NS * NS;
#pragma unroll
  for (int i = 0; i < 8; ++i)
#pragma unroll
    for (int j = 0; j < 4; ++j) {
      int rr = wr + 16 * i + 4 * fq;
      int cc = wc + 16 * j + fr;
      float ib = invB[cc];
#pragma unroll
      for (int p = 0; p < 4; ++p)
        Sb[(size_t)(tm + rr + p) * NS + tn + cc] =
            (_Float16)(acc[i][j][p] * invA[rr + p] * ib);
    }
}

// ---------------------------------------------------------------------------
// Kernel 3: init V=0, W=log_nu
__global__ __launch_bounds__(256) void init_kernel(float* __restrict__ V, float* __restrict__ W) {
  int i = blockIdx.x * 256 + threadIdx.x;  // 32768
  V[i] = 0.f;
  W[i] = LOG_INV_NS;
}

// ---------------------------------------------------------------------------
// Kernel 4 (u/row step): unchanged (2048 blocks, 8 blocks/CU, coalesced).
__global__ __launch_bounds__(256) void u_kernel(
    const _Float16* __restrict__ Sh, const float* __restrict__ W,
    float* __restrict__ U, float f) {
  __shared__ float Wt[8][65];
  int blk = blockIdx.x;
  int bs = blk & 7, rest = blk >> 3;
  int rowgrp = rest & 31, bq = rest >> 5;
  int b = bq * 8 + bs;
  int t = threadIdx.x;
#pragma unroll
  for (int i = 0; i < 2; ++i) {
    int idx = t + 256 * i;
    Wt[idx & 7][idx >> 3] = W[b * NS + idx];
  }
  __syncthreads();
  int w = t >> 6, l = t & 63;
  float wn[8];
#pragma unroll
  for (int e = 0; e < 8; ++e) wn[e] = Wt[e][l];
  int m0 = rowgrp * 16 + w * 4;
  const _Float16* Sb = Sh + ((size_t)b * NS + m0) * NS + 8 * l;
  float sum[4] = {0.f, 0.f, 0.f, 0.f};
#pragma unroll
  for (int k = 0; k < 4; ++k) {
    half8 hv = *(const half8*)(Sb + (size_t)k * NS);
#pragma unroll
    for (int e = 0; e < 8; ++e) sum[k] += __expf(fmaf(f, (float)hv[e], wn[e]));
  }
#pragma unroll
  for (int o = 32; o; o >>= 1) {
#pragma unroll
    for (int k = 0; k < 4; ++k) sum[k] += __shfl_xor(sum[k], o, 64);
  }
  if (l == 0) {
#pragma unroll
    for (int k = 0; k < 4; ++k)
      U[b * NS + m0 + k] = LOG_INV_NS - __logf(sum[k]);
  }
}

// ---------------------------------------------------------------------------
// Kernel 5 (v/col step): R12 high-occupancy version (1024 blocks).
__global__ __launch_bounds__(256) void v_kernel(
    const _Float16* __restrict__ Sh, const float* __restrict__ U,
    float* __restrict__ V, float* __restrict__ W,
    float f, int last, float* __restrict__ outPart) {
  __shared__ float Ul[NS];
  __shared__ float partC[64][33];
  __shared__ float partD[64][33];
  __shared__ float redC[4][33];
  __shared__ float redD[4][33];
  int blk = blockIdx.x;
  int b = blk & 63;
  int ng = blk >> 6;                // 0..15, 32 cols each
  int t = threadIdx.x;
  Ul[t] = U[b * NS + t];
  Ul[t + 256] = U[b * NS + t + 256];
  __syncthreads();

  int oct = t & 3;
  int mc = t >> 2;                  // m-chunk (8 rows), 0..63
  const _Float16* Sb = Sh + (size_t)b * NS * NS + (size_t)(mc * 8) * NS + ng * 32 + oct * 8;
  float c[8] = {}, d[8] = {};
#pragma unroll
  for (int i = 0; i < 8; ++i) {
    half8 hv = *(const half8*)(Sb + (size_t)i * NS);
    float um = Ul[mc * 8 + i];
#pragma unroll
    for (int e = 0; e < 8; ++e) {
      float sv = (float)hv[e];
      float ev = __expf(fmaf(f, sv, um));
      c[e] += ev;
      d[e] = fmaf(sv, ev, d[e]);
    }
  }
#pragma unroll
  for (int e = 0; e < 8; ++e) {
    partC[mc][oct * 8 + e] = c[e];
    partD[mc][oct * 8 + e] = d[e];
  }
  __syncthreads();
  {
    int ci = t & 31, seg = t >> 5;
    float cc = 0.f, dd = 0.f;
#pragma unroll
    for (int k = 0; k < 8; ++k) {
      cc += partC[seg * 8 + k][ci];
      dd += partD[seg * 8 + k][ci];
    }
    cc += __shfl_xor(cc, 32, 64);
    dd += __shfl_xor(dd, 32, 64);
    int w = t >> 6, l = t & 63;
    if (l < 32) { redC[w][l] = cc; redD[w][l] = dd; }
  }
  __syncthreads();
  if (t < 32) {
    float cc = redC[0][t] + redC[1][t] + redC[2][t] + redC[3][t];
    float vnew = LOG_INV_NS - __logf(cc);
    int n = b * NS + ng * 32 + t;
    float vold = V[n];
    V[n] = vnew;
    W[n] = 2.f * vnew - vold;
    if (last) {
      float dd = redD[0][t] + redD[1][t] + redD[2][t] + redD[3][t];
      float r = dd / cc;
      r += __shfl_xor(r, 16, 64);
      r += __shfl_xor(r, 8, 64);
      r += __shfl_xor(r, 4, 64);
      r += __shfl_xor(r, 2, 64);
      r += __shfl_xor(r, 1, 64);
      if (t == 0) outPart[b * 16 + ng] = r * (1.0f / (float)NS);
    }
  }
}

// ---------------------------------------------------------------------------
// Kernel 6: combine 16 partials per batch (deterministic)
__global__ void combine_kernel(const float* __restrict__ outPart, float* __restrict__ out) {
  int b = threadIdx.x;  // 64 threads
  float s = 0.f;
#pragma unroll
  for (int k = 0; k < 16; ++k) s += outPart[b * 16 + k];
  out[b] = s;
}

// ---------------------------------------------------------------------------
extern "C" void kernel_launch(void* const* d_in, const int* in_sizes, int n_in,
                              void* d_out, int out_size, void* d_ws, size_t ws_size,
                              hipStream_t stream) {
  (void)in_sizes; (void)n_in; (void)out_size; (void)ws_size;
  const float* x = (const float*)d_in[0];
  const float* y = (const float*)d_in[1];
  float* out = (float*)d_out;

  char* ws = (char*)d_ws;
  _Float16* Sh = (_Float16*)ws;                                // 32 MiB
  float* fregion = (float*)(ws + (size_t)NB * NS * NS * 2);
  float* U = fregion;                                          // 32768
  float* V = U + NB * NS;
  float* W = V + NB * NS;
  float* outPart = W + NB * NS;                                // 1024

  gemm_fused<<<256, 512, 0, stream>>>(x, y, Sh);
  init_kernel<<<(NB * NS) / 256, 256, 0, stream>>>(V, W);

  for (int t = 1; t <= NITERS; ++t) {
    float f = 10.0f * (float)t;
    u_kernel<<<2048, 256, 0, stream>>>(Sh, W, U, f);
    v_kernel<<<1024, 256, 0, stream>>>(Sh, U, V, W, f, t == NITERS ? 1 : 0, outPart);
  }
  combine_kernel<<<1, 64, 0, stream>>>(outPart, out);
}